// Round 7
// baseline (260.299 us; speedup 1.0000x reference)
//
#include <hip/hip_runtime.h>
#include <hip/hip_bf16.h>
#include <math.h>

#define T_SEQ 4096
#define EMB   1024
#define NH    8
#define HD    128
#define HALF  64

typedef __hip_bfloat16 bf16;
typedef __attribute__((ext_vector_type(8))) short short8;
typedef __attribute__((ext_vector_type(4))) short short4v;
typedef __attribute__((ext_vector_type(4))) float float4v;

static __device__ __forceinline__ float b2f(bf16 v) { return __bfloat162float(v); }
static __device__ __forceinline__ bf16  f2b(float v) { return __float2bfloat16(v); }
static __device__ __forceinline__ short f2bs(float v) {
    bf16 h = __float2bfloat16(v); short s; __builtin_memcpy(&s, &h, 2); return s;
}
static __device__ __forceinline__ float bs2f(short s) {
    bf16 h; __builtin_memcpy(&h, &s, 2); return __bfloat162float(h);
}
// async global->LDS, 16B per lane; lds base must be wave-uniform
static __device__ __forceinline__ void gload16(const short* g, short* l) {
    __builtin_amdgcn_global_load_lds((__attribute__((address_space(1))) void*)g,
                                     (__attribute__((address_space(3))) void*)l, 16, 0, 0);
}

// ---------------------------------------------------------------------------
// Converters, fused: z<4 -> weight transpose W[k][n] fp32 -> wbT[z][n][k] bf16;
// z==4 -> straight x fp32 -> bf16 (64x64 tiles).
// ---------------------------------------------------------------------------
__global__ __launch_bounds__(256) void convert_all(
    const float* __restrict__ w0, const float* __restrict__ w1,
    const float* __restrict__ w2, const float* __restrict__ w3,
    const float* __restrict__ x,
    short* __restrict__ wbT, short* __restrict__ xb)
{
    const int tid = threadIdx.x;
    if (blockIdx.z == 4) {
        const int r0 = blockIdx.x * 64;     // 16 blocks in x -> rows... need 4096 rows
        const int c0 = blockIdx.y * 64;
        // grid x covers 16 tiles -> but x has 64 row-tiles; use both: rows = x*... 
        // handled by caller: grid (64, 16, z==4 slice uses x=row-tile (64), y=col-tile (16))
        #pragma unroll
        for (int t = 0; t < 4; ++t) {
            int id = tid + t*256;
            int r = id >> 4, c4 = id & 15;
            float4 f = *(const float4*)(x + (size_t)(r0+r)*EMB + c0 + c4*4);
            short4v s = { f2bs(f.x), f2bs(f.y), f2bs(f.z), f2bs(f.w) };
            *(short4v*)(xb + (size_t)(r0+r)*EMB + c0 + c4*4) = s;
        }
        return;
    }
    const float* W = (blockIdx.z==0)?w0:(blockIdx.z==1)?w1:(blockIdx.z==2)?w2:w3;
    short* dst = wbT + (size_t)blockIdx.z * EMB * EMB;
    __shared__ float tile[64][65];
    const int k0 = (blockIdx.x & 15) * 64;
    const int n0 = blockIdx.y * 64;
    #pragma unroll
    for (int t = 0; t < 4; ++t) {
        int id = tid + t*256;
        int r = id >> 4, c4 = id & 15;
        float4 f = *(const float4*)(W + (size_t)(k0+r)*EMB + n0 + c4*4);
        tile[r][c4*4+0]=f.x; tile[r][c4*4+1]=f.y; tile[r][c4*4+2]=f.z; tile[r][c4*4+3]=f.w;
    }
    __syncthreads();
    #pragma unroll
    for (int t = 0; t < 4; ++t) {
        int id = tid + t*256;
        int n = id >> 4, k4 = id & 15;
        short4v s;
        #pragma unroll
        for (int j = 0; j < 4; ++j) s[j] = f2bs(tile[k4*4+j][n]);
        *(short4v*)(dst + (size_t)(n0+n)*EMB + k0 + k4*4) = s;
    }
}

// ---------------------------------------------------------------------------
// MFMA GEMM + fused RoPE/RMS epilogue for q,k. C[4096,3072] = xb @ wbT^T.
// 128x128 tile, BK=32. For z<2 the 128-col tile is one full head: restage C
// in LDS, apply rope+rms per row (numerics identical to separate pass).
// ---------------------------------------------------------------------------
__global__ __launch_bounds__(256) void qkv_gemm_mfma(
    const short* __restrict__ xb, const short* __restrict__ wbT,
    const float* __restrict__ cosb, const float* __restrict__ sinb,
    short* __restrict__ qb, short* __restrict__ kb, short* __restrict__ vb)
{
    __shared__ short As[128*32];
    __shared__ short Bs[128*32];
    __shared__ short Cs[128*132];   // rope restage, stride 132 (4-way max on reads)
    const int n0g = blockIdx.x * 128;
    const int m0  = blockIdx.y * 128;
    const int z   = n0g >> 10;
    const int ncol0 = n0g & 1023;
    const int tid = threadIdx.x;
    const int wv = tid >> 6, lane = tid & 63;
    const int cl = lane & 15, q = lane >> 4;
    const int wm = wv >> 1, wn = wv & 1;
    const int lrow = lane >> 2;
    const int lcol = (lane & 3) * 8;
    float4v acc[4][4];
    #pragma unroll
    for (int mi=0;mi<4;++mi)
        #pragma unroll
        for (int ni=0;ni<4;++ni) acc[mi][ni]=(float4v){0.f,0.f,0.f,0.f};

    for (int k0 = 0; k0 < EMB; k0 += 32) {
        __syncthreads();
        #pragma unroll
        for (int t = 0; t < 2; ++t) {
            int chunk = wv*2 + t;
            gload16(xb  + (size_t)(m0  + chunk*16 + lrow)*EMB + k0 + lcol, &As[chunk*512]);
            gload16(wbT + (size_t)(n0g + chunk*16 + lrow)*EMB + k0 + lcol, &Bs[chunk*512]);
        }
        __syncthreads();
        short8 af[4], bfr[4];
        #pragma unroll
        for (int mi=0;mi<4;++mi) af[mi]  = *(const short8*)&As[(wm*64+mi*16+cl)*32 + q*8];
        #pragma unroll
        for (int ni=0;ni<4;++ni) bfr[ni] = *(const short8*)&Bs[(wn*64+ni*16+cl)*32 + q*8];
        #pragma unroll
        for (int mi=0;mi<4;++mi)
            #pragma unroll
            for (int ni=0;ni<4;++ni)
                acc[mi][ni] = __builtin_amdgcn_mfma_f32_16x16x32_bf16(af[mi], bfr[ni], acc[mi][ni], 0, 0, 0);
    }

    if (z == 2) {   // v: plain store
        #pragma unroll
        for (int mi=0;mi<4;++mi)
            #pragma unroll
            for (int ni=0;ni<4;++ni)
                #pragma unroll
                for (int r=0;r<4;++r)
                    vb[(size_t)(m0+wm*64+mi*16+q*4+r)*EMB + ncol0 + wn*64+ni*16+cl] = f2bs(acc[mi][ni][r]);
        return;
    }
    // q/k: restage C tile (bf16) into LDS, then rope+rms per row
    #pragma unroll
    for (int mi=0;mi<4;++mi)
        #pragma unroll
        for (int ni=0;ni<4;++ni)
            #pragma unroll
            for (int r=0;r<4;++r)
                Cs[(wm*64+mi*16+q*4+r)*132 + wn*64+ni*16+cl] = f2bs(acc[mi][ni][r]);
    __syncthreads();
    if (tid < 128) {
        const int r = tid;                 // row within tile
        const int t = m0 + r;              // sequence position
        const int h = ncol0 >> 7;          // head
        short* dst = ((z == 0) ? qb : kb) + (size_t)t*EMB + h*HD;
        // pass 1: sum of squares after rope
        float ss = 0.f;
        #pragma unroll
        for (int c = 0; c < 16; ++c) {
            short4v a1 = *(const short4v*)&Cs[r*132 + c*4];
            short4v a2 = *(const short4v*)&Cs[r*132 + 64 + c*4];
            float4 cc = *(const float4*)(cosb + (size_t)t*HALF + c*4);
            float4 sn = *(const float4*)(sinb + (size_t)t*HALF + c*4);
            float cv[4] = {cc.x, cc.y, cc.z, cc.w};
            float sv[4] = {sn.x, sn.y, sn.z, sn.w};
            #pragma unroll
            for (int j = 0; j < 4; ++j) {
                float x1 = bs2f(a1[j]), x2 = bs2f(a2[j]);
                float y1 = x1*cv[j] + x2*sv[j];
                float y2 = x2*cv[j] - x1*sv[j];
                ss += y1*y1 + y2*y2;
            }
        }
        const float rr = rsqrtf(ss * (1.0f/HD) + 1e-6f);
        // pass 2: recompute, scale, vector store
        #pragma unroll
        for (int c = 0; c < 16; ++c) {
            short4v a1 = *(const short4v*)&Cs[r*132 + c*4];
            short4v a2 = *(const short4v*)&Cs[r*132 + 64 + c*4];
            float4 cc = *(const float4*)(cosb + (size_t)t*HALF + c*4);
            float4 sn = *(const float4*)(sinb + (size_t)t*HALF + c*4);
            float cv[4] = {cc.x, cc.y, cc.z, cc.w};
            float sv[4] = {sn.x, sn.y, sn.z, sn.w};
            short4v o1, o2;
            #pragma unroll
            for (int j = 0; j < 4; ++j) {
                float x1 = bs2f(a1[j]), x2 = bs2f(a2[j]);
                float y1 = x1*cv[j] + x2*sv[j];
                float y2 = x2*cv[j] - x1*sv[j];
                o1[j] = f2bs(y1*rr);
                o2[j] = f2bs(y2*rr);
            }
            *(short4v*)(dst + c*4)        = o1;
            *(short4v*)(dst + HALF + c*4) = o2;
        }
    }
}

// ---------------------------------------------------------------------------
// MFMA GEMM: out[4096,1024] fp32 = yb(bf16) @ wpT^T
// ---------------------------------------------------------------------------
__global__ __launch_bounds__(256) void proj_gemm_mfma(
    const short* __restrict__ yb, const short* __restrict__ wpT,
    float* __restrict__ out)
{
    __shared__ short As[128*32];
    __shared__ short Bs[128*32];
    const int n0 = blockIdx.x * 128;
    const int m0 = blockIdx.y * 128;
    const int tid = threadIdx.x;
    const int wv = tid >> 6, lane = tid & 63;
    const int cl = lane & 15, q = lane >> 4;
    const int wm = wv >> 1, wn = wv & 1;
    const int lrow = lane >> 2;
    const int lcol = (lane & 3) * 8;
    float4v acc[4][4];
    #pragma unroll
    for (int mi=0;mi<4;++mi)
        #pragma unroll
        for (int ni=0;ni<4;++ni) acc[mi][ni]=(float4v){0.f,0.f,0.f,0.f};

    for (int k0 = 0; k0 < EMB; k0 += 32) {
        __syncthreads();
        #pragma unroll
        for (int t = 0; t < 2; ++t) {
            int chunk = wv*2 + t;
            gload16(yb  + (size_t)(m0 + chunk*16 + lrow)*EMB + k0 + lcol, &As[chunk*512]);
            gload16(wpT + (size_t)(n0 + chunk*16 + lrow)*EMB + k0 + lcol, &Bs[chunk*512]);
        }
        __syncthreads();
        short8 af[4], bfr[4];
        #pragma unroll
        for (int mi=0;mi<4;++mi) af[mi]  = *(const short8*)&As[(wm*64+mi*16+cl)*32 + q*8];
        #pragma unroll
        for (int ni=0;ni<4;++ni) bfr[ni] = *(const short8*)&Bs[(wn*64+ni*16+cl)*32 + q*8];
        #pragma unroll
        for (int mi=0;mi<4;++mi)
            #pragma unroll
            for (int ni=0;ni<4;++ni)
                acc[mi][ni] = __builtin_amdgcn_mfma_f32_16x16x32_bf16(af[mi], bfr[ni], acc[mi][ni], 0, 0, 0);
    }
    #pragma unroll
    for (int mi=0;mi<4;++mi)
        #pragma unroll
        for (int ni=0;ni<4;++ni)
            #pragma unroll
            for (int r=0;r<4;++r)
                out[(size_t)(m0+wm*64+mi*16+q*4+r)*EMB + n0 + wn*64+ni*16+cl] = acc[mi][ni][r];
}

// ---------------------------------------------------------------------------
// Fused gate + ve-add + transpose: vt[h][d][t] = vb[t][h,d] + g(t,h)*ve[t][h,d]
// ---------------------------------------------------------------------------
__global__ __launch_bounds__(256) void gate_vt(
    const float* __restrict__ x, const float* __restrict__ ve,
    const float* __restrict__ wg, const short* __restrict__ vb,
    short* __restrict__ vt)
{
    const int t0 = blockIdx.x * 64;
    const int d0 = blockIdx.y * 64;
    const int h  = blockIdx.z;
    const int tid = threadIdx.x;
    __shared__ short tile[64][68];
    __shared__ float g[64];
    if (tid < 64) {
        float s = 0.f;
        #pragma unroll
        for (int c = 0; c < 32; ++c)
            s += x[(size_t)(t0+tid)*EMB + c] * wg[c*NH + h];
        g[tid] = 2.f / (1.f + __expf(-s));
    }
    __syncthreads();
    #pragma unroll
    for (int k = 0; k < 4; ++k) {
        int id = tid + k*256;
        int r = id >> 4, c4 = id & 15;
        short4v vr = *(const short4v*)(vb + (size_t)(t0+r)*EMB + h*HD + d0 + c4*4);
        float4 vex = *(const float4*)(ve + (size_t)(t0+r)*EMB + h*HD + d0 + c4*4);
        float gr = g[r];
        short4v o;
        o[0] = f2bs(bs2f(vr[0]) + gr*vex.x);
        o[1] = f2bs(bs2f(vr[1]) + gr*vex.y);
        o[2] = f2bs(bs2f(vr[2]) + gr*vex.z);
        o[3] = f2bs(bs2f(vr[3]) + gr*vex.w);
        *(short4v*)&tile[r][c4*4] = o;
    }
    __syncthreads();
    #pragma unroll
    for (int k = 0; k < 4; ++k) {
        int id = tid + k*256;
        int dr = id >> 4, tg = id & 15;
        short4v w;
        #pragma unroll
        for (int j = 0; j < 4; ++j) w[j] = tile[tg*4+j][dr];
        *(short4v*)(vt + (size_t)(h*HD + d0 + dr)*T_SEQ + t0 + tg*4) = w;
    }
}

// ---------------------------------------------------------------------------
// Flash attention, MFMA 16x16x32 bf16. One block = 64 queries x 1 head.
// grid = (head, qtile): head indexes the XCD so each XCD's L2 holds one
// head's K/V working set (4.2 MB < 4 MB L2 + tight reuse window).
// ---------------------------------------------------------------------------
__global__ __launch_bounds__(256) void attn_flash(
    const bf16* __restrict__ qbh, const bf16* __restrict__ kbh,
    const bf16* __restrict__ vth, bf16* __restrict__ ybh,
    const int* __restrict__ wptr)
{
    const short* qb = (const short*)qbh;
    const short* kb = (const short*)kbh;
    const short* vt = (const short*)vth;
    short* yb = (short*)ybh;

    __shared__ short Ks[64*136];
    __shared__ short Vs[128*72];
    __shared__ short Ps[4*16*72];

    int W = *wptr; W = min(max(W, 1), 1024);
    const int h  = blockIdx.x;
    const int i0 = blockIdx.y * 64;
    const int tid  = threadIdx.x;
    const int wv   = tid >> 6;
    const int lane = tid & 63;
    const int cl   = lane & 15;
    const int q    = lane >> 4;
    const int m0   = wv * 16;
    const float scale = 0.08838834764831845f;

    short8 qa[4];
    {
        const short* qbase = qb + (size_t)(i0 + m0 + cl) * EMB + h*HD + q*8;
        #pragma unroll
        for (int ks = 0; ks < 4; ++ks)
            qa[ks] = *(const short8*)(qbase + ks*32);
    }

    float4v o[8];
    #pragma unroll
    for (int n = 0; n < 8; ++n) o[n] = (float4v){0.f,0.f,0.f,0.f};
    float lrow[4] = {0.f,0.f,0.f,0.f};

    const int lo_key  = i0 - W + 1;
    const int jt_start = lo_key > 0 ? (lo_key >> 6) : 0;
    const int jt_end   = i0 >> 6;

    const int kkey[4] = { (tid+0)>>4, (tid+256)>>4, (tid+512)>>4, (tid+768)>>4 };
    const int kc16 = tid & 15;
    const int vd[4] = { (tid+0)>>3, (tid+256)>>3, (tid+512)>>3, (tid+768)>>3 };
    const int vc8 = tid & 7;

    short8 kreg[4], vreg[4];
    {
        const int j0 = jt_start << 6;
        #pragma unroll
        for (int kk = 0; kk < 4; ++kk) {
            kreg[kk] = *(const short8*)(kb + (size_t)(j0+kkey[kk])*EMB + h*HD + kc16*8);
            vreg[kk] = *(const short8*)(vt + (size_t)(h*HD + vd[kk])*T_SEQ + j0 + vc8*8);
        }
    }

    for (int jt = jt_start; jt <= jt_end; ++jt) {
        const int j0 = jt << 6;
        __syncthreads();
        #pragma unroll
        for (int kk = 0; kk < 4; ++kk) {
            *(short8*)&Ks[kkey[kk]*136 + kc16*8] = kreg[kk];
            *(short8*)&Vs[vd[kk]*72 + vc8*8]     = vreg[kk];
        }
        __syncthreads();
        if (jt < jt_end) {
            const int j0n = j0 + 64;
            #pragma unroll
            for (int kk = 0; kk < 4; ++kk) {
                kreg[kk] = *(const short8*)(kb + (size_t)(j0n+kkey[kk])*EMB + h*HD + kc16*8);
                vreg[kk] = *(const short8*)(vt + (size_t)(h*HD + vd[kk])*T_SEQ + j0n + vc8*8);
            }
        }

        float4v s[4];
        #pragma unroll
        for (int nt = 0; nt < 4; ++nt) {
            s[nt] = (float4v){0.f,0.f,0.f,0.f};
            #pragma unroll
            for (int ks = 0; ks < 4; ++ks) {
                short8 kf = *(const short8*)&Ks[(nt*16 + cl)*136 + ks*32 + q*8];
                s[nt] = __builtin_amdgcn_mfma_f32_16x16x32_bf16(qa[ks], kf, s[nt], 0, 0, 0);
            }
        }
        const bool needmask = (j0 + 63 > i0) || (j0 < i0 + 64 - W);
        #pragma unroll
        for (int nt = 0; nt < 4; ++nt) {
            #pragma unroll
            for (int r = 0; r < 4; ++r) {
                float sv = s[nt][r] * scale;
                if (needmask) {
                    int j    = j0 + nt*16 + cl;
                    int irow = i0 + m0 + q*4 + r;
                    if (j > irow || j <= irow - W) sv = -1e30f;
                }
                s[nt][r] = __expf(sv);
            }
        }
        #pragma unroll
        for (int r = 0; r < 4; ++r)
            lrow[r] += s[0][r] + s[1][r] + s[2][r] + s[3][r];
        #pragma unroll
        for (int nt = 0; nt < 4; ++nt)
            #pragma unroll
            for (int r = 0; r < 4; ++r)
                Ps[wv*1152 + (q*4+r)*72 + nt*16 + cl] = f2bs(s[nt][r]);
        short8 pa[2];
        #pragma unroll
        for (int k2 = 0; k2 < 2; ++k2)
            pa[k2] = *(const short8*)&Ps[wv*1152 + cl*72 + k2*32 + q*8];
        #pragma unroll
        for (int n = 0; n < 8; ++n) {
            #pragma unroll
            for (int k2 = 0; k2 < 2; ++k2) {
                short8 vf = *(const short8*)&Vs[(n*16 + cl)*72 + k2*32 + q*8];
                o[n] = __builtin_amdgcn_mfma_f32_16x16x32_bf16(pa[k2], vf, o[n], 0, 0, 0);
            }
        }
    }
    #pragma unroll
    for (int r = 0; r < 4; ++r) {
        float t = lrow[r];
        t += __shfl_xor(t, 1);
        t += __shfl_xor(t, 2);
        t += __shfl_xor(t, 4);
        t += __shfl_xor(t, 8);
        float inv = 1.f / t;
        int row = i0 + m0 + q*4 + r;
        #pragma unroll
        for (int n = 0; n < 8; ++n)
            yb[(size_t)row*EMB + h*HD + n*16 + cl] = f2bs(o[n][r] * inv);
    }
}

// ---------------------------------------------------------------------------
extern "C" void kernel_launch(void* const* d_in, const int* in_sizes, int n_in,
                              void* d_out, int out_size, void* d_ws, size_t ws_size,
                              hipStream_t stream)
{
    const float* x    = (const float*)d_in[0];
    const float* ve   = (const float*)d_in[1];
    const float* cosb = (const float*)d_in[2];
    const float* sinb = (const float*)d_in[3];
    const float* wq   = (const float*)d_in[4];
    const float* wk   = (const float*)d_in[5];
    const float* wv   = (const float*)d_in[6];
    const float* wg   = (const float*)d_in[7];
    const float* wp   = (const float*)d_in[8];
    const int*   wsz  = (const int*)d_in[9];
    float* out = (float*)d_out;

    const size_t SEG = (size_t)T_SEQ * EMB;        // 4M elements = 8 MB bf16
    short* xb  = (short*)d_ws;                     // later reused as vt
    short* wbT = xb + SEG;                         // wq|wk|wv|wp transposed, 4x1M
    short* qb  = wbT + SEG;
    short* kb  = qb + SEG;
    short* vb  = kb + SEG;                         // 40 MB total
    short* vt  = xb;                               // alias: xb dead after qkv gemm
    short* yb  = vb;                               // alias: vb dead after gate_vt

    // z=0..3: weight transpose+convert (grid.x uses low 4 bits); z=4: x convert
    convert_all<<<dim3(64, 16, 5), 256, 0, stream>>>(wq, wk, wv, wp, x, wbT, xb);
    qkv_gemm_mfma<<<dim3(24, 32), 256, 0, stream>>>(xb, wbT, cosb, sinb, qb, kb, vb);
    gate_vt<<<dim3(T_SEQ/64, HD/64, NH), 256, 0, stream>>>(x, ve, wg, vb, vt);
    attn_flash<<<dim3(NH, T_SEQ/64), 256, 0, stream>>>((bf16*)qb, (bf16*)kb, (bf16*)vt, (bf16*)yb, wsz);
    proj_gemm_mfma<<<dim3(8, 32), 256, 0, stream>>>(yb, wbT + (size_t)3*EMB*EMB, out);
}

// Round 8
// 222.130 us; speedup vs baseline: 1.1718x; 1.1718x over previous
//
#include <hip/hip_runtime.h>
#include <hip/hip_bf16.h>
#include <math.h>

#define T_SEQ 4096
#define EMB   1024
#define NH    8
#define HD    128
#define HALF  64

typedef __hip_bfloat16 bf16;
typedef __attribute__((ext_vector_type(8))) short short8;
typedef __attribute__((ext_vector_type(4))) short short4v;
typedef __attribute__((ext_vector_type(4))) float float4v;

static __device__ __forceinline__ float b2f(bf16 v) { return __bfloat162float(v); }
static __device__ __forceinline__ bf16  f2b(float v) { return __float2bfloat16(v); }
static __device__ __forceinline__ short f2bs(float v) {
    bf16 h = __float2bfloat16(v); short s; __builtin_memcpy(&s, &h, 2); return s;
}
static __device__ __forceinline__ float bs2f(short s) {
    bf16 h; __builtin_memcpy(&h, &s, 2); return __bfloat162float(h);
}
// async global->LDS, 16B per lane; lds base must be wave-uniform
static __device__ __forceinline__ void gload16(const short* g, short* l) {
    __builtin_amdgcn_global_load_lds((__attribute__((address_space(1))) void*)g,
                                     (__attribute__((address_space(3))) void*)l, 16, 0, 0);
}

// ---------------------------------------------------------------------------
// Converters, fused: z<4 -> weight transpose W[k][n] fp32 -> wbT[z][n][k] bf16
// (16 x-blocks; rest early-exit); z==4 -> x fp32 -> bf16 (64 x-blocks).
// ---------------------------------------------------------------------------
__global__ __launch_bounds__(256) void convert_all(
    const float* __restrict__ w0, const float* __restrict__ w1,
    const float* __restrict__ w2, const float* __restrict__ w3,
    const float* __restrict__ x,
    short* __restrict__ wbT, short* __restrict__ xb)
{
    const int tid = threadIdx.x;
    if (blockIdx.z == 4) {
        const int r0 = blockIdx.x * 64;
        const int c0 = blockIdx.y * 64;
        #pragma unroll
        for (int t = 0; t < 4; ++t) {
            int id = tid + t*256;
            int r = id >> 4, c4 = id & 15;
            float4 f = *(const float4*)(x + (size_t)(r0+r)*EMB + c0 + c4*4);
            short4v s = { f2bs(f.x), f2bs(f.y), f2bs(f.z), f2bs(f.w) };
            *(short4v*)(xb + (size_t)(r0+r)*EMB + c0 + c4*4) = s;
        }
        return;
    }
    if (blockIdx.x >= 16) return;          // weights need only 16 k-tiles
    const float* W = (blockIdx.z==0)?w0:(blockIdx.z==1)?w1:(blockIdx.z==2)?w2:w3;
    short* dst = wbT + (size_t)blockIdx.z * EMB * EMB;
    __shared__ float tile[64][65];
    const int k0 = blockIdx.x * 64;
    const int n0 = blockIdx.y * 64;
    #pragma unroll
    for (int t = 0; t < 4; ++t) {
        int id = tid + t*256;
        int r = id >> 4, c4 = id & 15;
        float4 f = *(const float4*)(W + (size_t)(k0+r)*EMB + n0 + c4*4);
        tile[r][c4*4+0]=f.x; tile[r][c4*4+1]=f.y; tile[r][c4*4+2]=f.z; tile[r][c4*4+3]=f.w;
    }
    __syncthreads();
    #pragma unroll
    for (int t = 0; t < 4; ++t) {
        int id = tid + t*256;
        int n = id >> 4, k4 = id & 15;
        short4v s;
        #pragma unroll
        for (int j = 0; j < 4; ++j) s[j] = f2bs(tile[k4*4+j][n]);
        *(short4v*)(dst + (size_t)(n0+n)*EMB + k0 + k4*4) = s;
    }
}

// ---------------------------------------------------------------------------
// MFMA GEMM + register-resident RoPE/RMS epilogue. C[4096,3072] = xb @ wbT^T.
// 128x128 tile, BK=32. Wave wv owns rows wv*32..wv*32+31 x ALL 128 cols
// (2x8 MFMA grid) so each output row (and its rope pair d,d+64 = ni,ni+4)
// lives in one wave -> no LDS restage, in-wave shfl for RMS.
// ---------------------------------------------------------------------------
__global__ __launch_bounds__(256) void qkv_gemm_mfma(
    const short* __restrict__ xb, const short* __restrict__ wbT,
    const float* __restrict__ cosb, const float* __restrict__ sinb,
    short* __restrict__ qb, short* __restrict__ kb, short* __restrict__ vb)
{
    __shared__ short As[128*32];
    __shared__ short Bs[128*32];
    const int n0g = blockIdx.x * 128;
    const int m0  = blockIdx.y * 128;
    const int z   = n0g >> 10;
    const int ncol0 = n0g & 1023;
    const int tid = threadIdx.x;
    const int wv = tid >> 6, lane = tid & 63;
    const int cl = lane & 15, q = lane >> 4;
    const int lrow = lane >> 2;
    const int lcol = (lane & 3) * 8;
    float4v acc[2][8];
    #pragma unroll
    for (int mi=0;mi<2;++mi)
        #pragma unroll
        for (int ni=0;ni<8;++ni) acc[mi][ni]=(float4v){0.f,0.f,0.f,0.f};

    for (int k0 = 0; k0 < EMB; k0 += 32) {
        __syncthreads();
        #pragma unroll
        for (int t = 0; t < 2; ++t) {
            int chunk = wv*2 + t;
            gload16(xb  + (size_t)(m0  + chunk*16 + lrow)*EMB + k0 + lcol, &As[chunk*512]);
            gload16(wbT + (size_t)(n0g + chunk*16 + lrow)*EMB + k0 + lcol, &Bs[chunk*512]);
        }
        __syncthreads();
        short8 af[2], bfr[8];
        #pragma unroll
        for (int mi=0;mi<2;++mi) af[mi]  = *(const short8*)&As[(wv*32+mi*16+cl)*32 + q*8];
        #pragma unroll
        for (int ni=0;ni<8;++ni) bfr[ni] = *(const short8*)&Bs[(ni*16+cl)*32 + q*8];
        #pragma unroll
        for (int mi=0;mi<2;++mi)
            #pragma unroll
            for (int ni=0;ni<8;++ni)
                acc[mi][ni] = __builtin_amdgcn_mfma_f32_16x16x32_bf16(af[mi], bfr[ni], acc[mi][ni], 0, 0, 0);
    }

    if (z == 2) {   // v: plain store
        #pragma unroll
        for (int mi=0;mi<2;++mi)
            #pragma unroll
            for (int ni=0;ni<8;++ni)
                #pragma unroll
                for (int r=0;r<4;++r)
                    vb[(size_t)(m0+wv*32+mi*16+q*4+r)*EMB + ncol0 + ni*16+cl] = f2bs(acc[mi][ni][r]);
        return;
    }
    // q/k: rope + rms entirely in registers (pair (d,d+64) = (ni, ni+4))
    const int h = ncol0 >> 7;
    short* dstb = (z == 0) ? qb : kb;
    #pragma unroll
    for (int mi=0;mi<2;++mi) {
        #pragma unroll
        for (int r=0;r<4;++r) {
            const int t = m0 + wv*32 + mi*16 + q*4 + r;
            float y1[4], y2[4];
            float ss = 0.f;
            #pragma unroll
            for (int ni=0;ni<4;++ni) {
                const int d = ni*16 + cl;
                float c = cosb[(size_t)t*HALF + d];
                float s = sinb[(size_t)t*HALF + d];
                float x1 = acc[mi][ni][r];
                float x2 = acc[mi][ni+4][r];
                y1[ni] = x1*c + x2*s;
                y2[ni] = x2*c - x1*s;
                ss += y1[ni]*y1[ni] + y2[ni]*y2[ni];
            }
            ss += __shfl_xor(ss, 1);
            ss += __shfl_xor(ss, 2);
            ss += __shfl_xor(ss, 4);
            ss += __shfl_xor(ss, 8);
            const float rr = rsqrtf(ss * (1.0f/HD) + 1e-6f);
            short* dst = dstb + (size_t)t*EMB + h*HD;
            #pragma unroll
            for (int ni=0;ni<4;++ni) {
                dst[ni*16 + cl]        = f2bs(y1[ni]*rr);
                dst[ni*16 + cl + HALF] = f2bs(y2[ni]*rr);
            }
        }
    }
}

// ---------------------------------------------------------------------------
// MFMA GEMM: out[4096,1024] fp32 = yb(bf16) @ wpT^T
// ---------------------------------------------------------------------------
__global__ __launch_bounds__(256) void proj_gemm_mfma(
    const short* __restrict__ yb, const short* __restrict__ wpT,
    float* __restrict__ out)
{
    __shared__ short As[128*32];
    __shared__ short Bs[128*32];
    const int n0 = blockIdx.x * 128;
    const int m0 = blockIdx.y * 128;
    const int tid = threadIdx.x;
    const int wv = tid >> 6, lane = tid & 63;
    const int cl = lane & 15, q = lane >> 4;
    const int wm = wv >> 1, wn = wv & 1;
    const int lrow = lane >> 2;
    const int lcol = (lane & 3) * 8;
    float4v acc[4][4];
    #pragma unroll
    for (int mi=0;mi<4;++mi)
        #pragma unroll
        for (int ni=0;ni<4;++ni) acc[mi][ni]=(float4v){0.f,0.f,0.f,0.f};

    for (int k0 = 0; k0 < EMB; k0 += 32) {
        __syncthreads();
        #pragma unroll
        for (int t = 0; t < 2; ++t) {
            int chunk = wv*2 + t;
            gload16(yb  + (size_t)(m0 + chunk*16 + lrow)*EMB + k0 + lcol, &As[chunk*512]);
            gload16(wpT + (size_t)(n0 + chunk*16 + lrow)*EMB + k0 + lcol, &Bs[chunk*512]);
        }
        __syncthreads();
        short8 af[4], bfr[4];
        #pragma unroll
        for (int mi=0;mi<4;++mi) af[mi]  = *(const short8*)&As[(wm*64+mi*16+cl)*32 + q*8];
        #pragma unroll
        for (int ni=0;ni<4;++ni) bfr[ni] = *(const short8*)&Bs[(wn*64+ni*16+cl)*32 + q*8];
        #pragma unroll
        for (int mi=0;mi<4;++mi)
            #pragma unroll
            for (int ni=0;ni<4;++ni)
                acc[mi][ni] = __builtin_amdgcn_mfma_f32_16x16x32_bf16(af[mi], bfr[ni], acc[mi][ni], 0, 0, 0);
    }
    #pragma unroll
    for (int mi=0;mi<4;++mi)
        #pragma unroll
        for (int ni=0;ni<4;++ni)
            #pragma unroll
            for (int r=0;r<4;++r)
                out[(size_t)(m0+wm*64+mi*16+q*4+r)*EMB + n0 + wn*64+ni*16+cl] = acc[mi][ni][r];
}

// ---------------------------------------------------------------------------
// Fused gate + ve-add + transpose: vt[h][d][t] = vb[t][h,d] + g(t,h)*ve[t][h,d]
// ---------------------------------------------------------------------------
__global__ __launch_bounds__(256) void gate_vt(
    const float* __restrict__ x, const float* __restrict__ ve,
    const float* __restrict__ wg, const short* __restrict__ vb,
    short* __restrict__ vt)
{
    const int t0 = blockIdx.x * 64;
    const int d0 = blockIdx.y * 64;
    const int h  = blockIdx.z;
    const int tid = threadIdx.x;
    __shared__ short tile[64][68];
    __shared__ float g[64];
    if (tid < 64) {
        float s = 0.f;
        #pragma unroll
        for (int c = 0; c < 32; ++c)
            s += x[(size_t)(t0+tid)*EMB + c] * wg[c*NH + h];
        g[tid] = 2.f / (1.f + __expf(-s));
    }
    __syncthreads();
    #pragma unroll
    for (int k = 0; k < 4; ++k) {
        int id = tid + k*256;
        int r = id >> 4, c4 = id & 15;
        short4v vr = *(const short4v*)(vb + (size_t)(t0+r)*EMB + h*HD + d0 + c4*4);
        float4 vex = *(const float4*)(ve + (size_t)(t0+r)*EMB + h*HD + d0 + c4*4);
        float gr = g[r];
        short4v o;
        o[0] = f2bs(bs2f(vr[0]) + gr*vex.x);
        o[1] = f2bs(bs2f(vr[1]) + gr*vex.y);
        o[2] = f2bs(bs2f(vr[2]) + gr*vex.z);
        o[3] = f2bs(bs2f(vr[3]) + gr*vex.w);
        *(short4v*)&tile[r][c4*4] = o;
    }
    __syncthreads();
    #pragma unroll
    for (int k = 0; k < 4; ++k) {
        int id = tid + k*256;
        int dr = id >> 4, tg = id & 15;
        short4v w;
        #pragma unroll
        for (int j = 0; j < 4; ++j) w[j] = tile[tg*4+j][dr];
        *(short4v*)(vt + (size_t)(h*HD + d0 + dr)*T_SEQ + t0 + tg*4) = w;
    }
}

// ---------------------------------------------------------------------------
// Flash attention, MFMA 16x16x32 bf16. One block = 64 queries x 1 head.
// grid = (head, qtile) so linear%8 = head -> one head's K/V per XCD L2.
// ---------------------------------------------------------------------------
__global__ __launch_bounds__(256) void attn_flash(
    const bf16* __restrict__ qbh, const bf16* __restrict__ kbh,
    const bf16* __restrict__ vth, bf16* __restrict__ ybh,
    const int* __restrict__ wptr)
{
    const short* qb = (const short*)qbh;
    const short* kb = (const short*)kbh;
    const short* vt = (const short*)vth;
    short* yb = (short*)ybh;

    __shared__ short Ks[64*136];
    __shared__ short Vs[128*72];
    __shared__ short Ps[4*16*72];

    int W = *wptr; W = min(max(W, 1), 1024);
    const int h  = blockIdx.x;
    const int i0 = blockIdx.y * 64;
    const int tid  = threadIdx.x;
    const int wv   = tid >> 6;
    const int lane = tid & 63;
    const int cl   = lane & 15;
    const int q    = lane >> 4;
    const int m0   = wv * 16;
    const float scale = 0.08838834764831845f;

    short8 qa[4];
    {
        const short* qbase = qb + (size_t)(i0 + m0 + cl) * EMB + h*HD + q*8;
        #pragma unroll
        for (int ks = 0; ks < 4; ++ks)
            qa[ks] = *(const short8*)(qbase + ks*32);
    }

    float4v o[8];
    #pragma unroll
    for (int n = 0; n < 8; ++n) o[n] = (float4v){0.f,0.f,0.f,0.f};
    float lrow[4] = {0.f,0.f,0.f,0.f};

    const int lo_key  = i0 - W + 1;
    const int jt_start = lo_key > 0 ? (lo_key >> 6) : 0;
    const int jt_end   = i0 >> 6;

    const int kkey[4] = { (tid+0)>>4, (tid+256)>>4, (tid+512)>>4, (tid+768)>>4 };
    const int kc16 = tid & 15;
    const int vd[4] = { (tid+0)>>3, (tid+256)>>3, (tid+512)>>3, (tid+768)>>3 };
    const int vc8 = tid & 7;

    short8 kreg[4], vreg[4];
    {
        const int j0 = jt_start << 6;
        #pragma unroll
        for (int kk = 0; kk < 4; ++kk) {
            kreg[kk] = *(const short8*)(kb + (size_t)(j0+kkey[kk])*EMB + h*HD + kc16*8);
            vreg[kk] = *(const short8*)(vt + (size_t)(h*HD + vd[kk])*T_SEQ + j0 + vc8*8);
        }
    }

    for (int jt = jt_start; jt <= jt_end; ++jt) {
        const int j0 = jt << 6;
        __syncthreads();
        #pragma unroll
        for (int kk = 0; kk < 4; ++kk) {
            *(short8*)&Ks[kkey[kk]*136 + kc16*8] = kreg[kk];
            *(short8*)&Vs[vd[kk]*72 + vc8*8]     = vreg[kk];
        }
        __syncthreads();
        if (jt < jt_end) {
            const int j0n = j0 + 64;
            #pragma unroll
            for (int kk = 0; kk < 4; ++kk) {
                kreg[kk] = *(const short8*)(kb + (size_t)(j0n+kkey[kk])*EMB + h*HD + kc16*8);
                vreg[kk] = *(const short8*)(vt + (size_t)(h*HD + vd[kk])*T_SEQ + j0n + vc8*8);
            }
        }

        float4v s[4];
        #pragma unroll
        for (int nt = 0; nt < 4; ++nt) {
            s[nt] = (float4v){0.f,0.f,0.f,0.f};
            #pragma unroll
            for (int ks = 0; ks < 4; ++ks) {
                short8 kf = *(const short8*)&Ks[(nt*16 + cl)*136 + ks*32 + q*8];
                s[nt] = __builtin_amdgcn_mfma_f32_16x16x32_bf16(qa[ks], kf, s[nt], 0, 0, 0);
            }
        }
        const bool needmask = (j0 + 63 > i0) || (j0 < i0 + 64 - W);
        #pragma unroll
        for (int nt = 0; nt < 4; ++nt) {
            #pragma unroll
            for (int r = 0; r < 4; ++r) {
                float sv = s[nt][r] * scale;
                if (needmask) {
                    int j    = j0 + nt*16 + cl;
                    int irow = i0 + m0 + q*4 + r;
                    if (j > irow || j <= irow - W) sv = -1e30f;
                }
                s[nt][r] = __expf(sv);
            }
        }
        #pragma unroll
        for (int r = 0; r < 4; ++r)
            lrow[r] += s[0][r] + s[1][r] + s[2][r] + s[3][r];
        #pragma unroll
        for (int nt = 0; nt < 4; ++nt)
            #pragma unroll
            for (int r = 0; r < 4; ++r)
                Ps[wv*1152 + (q*4+r)*72 + nt*16 + cl] = f2bs(s[nt][r]);
        short8 pa[2];
        #pragma unroll
        for (int k2 = 0; k2 < 2; ++k2)
            pa[k2] = *(const short8*)&Ps[wv*1152 + cl*72 + k2*32 + q*8];
        #pragma unroll
        for (int n = 0; n < 8; ++n) {
            #pragma unroll
            for (int k2 = 0; k2 < 2; ++k2) {
                short8 vf = *(const short8*)&Vs[(n*16 + cl)*72 + k2*32 + q*8];
                o[n] = __builtin_amdgcn_mfma_f32_16x16x32_bf16(pa[k2], vf, o[n], 0, 0, 0);
            }
        }
    }
    #pragma unroll
    for (int r = 0; r < 4; ++r) {
        float t = lrow[r];
        t += __shfl_xor(t, 1);
        t += __shfl_xor(t, 2);
        t += __shfl_xor(t, 4);
        t += __shfl_xor(t, 8);
        float inv = 1.f / t;
        int row = i0 + m0 + q*4 + r;
        #pragma unroll
        for (int n = 0; n < 8; ++n)
            yb[(size_t)row*EMB + h*HD + n*16 + cl] = f2bs(o[n][r] * inv);
    }
}

// ---------------------------------------------------------------------------
extern "C" void kernel_launch(void* const* d_in, const int* in_sizes, int n_in,
                              void* d_out, int out_size, void* d_ws, size_t ws_size,
                              hipStream_t stream)
{
    const float* x    = (const float*)d_in[0];
    const float* ve   = (const float*)d_in[1];
    const float* cosb = (const float*)d_in[2];
    const float* sinb = (const float*)d_in[3];
    const float* wq   = (const float*)d_in[4];
    const float* wk   = (const float*)d_in[5];
    const float* wv   = (const float*)d_in[6];
    const float* wg   = (const float*)d_in[7];
    const float* wp   = (const float*)d_in[8];
    const int*   wsz  = (const int*)d_in[9];
    float* out = (float*)d_out;

    const size_t SEG = (size_t)T_SEQ * EMB;        // 4M elements = 8 MB bf16
    short* xb  = (short*)d_ws;                     // later reused as vt
    short* wbT = xb + SEG;                         // wq|wk|wv|wp transposed, 4x1M
    short* qb  = wbT + SEG;
    short* kb  = qb + SEG;
    short* vb  = kb + SEG;                         // 40 MB total
    short* vt  = xb;                               // alias: xb dead after qkv gemm
    short* yb  = vb;                               // alias: vb dead after gate_vt

    convert_all<<<dim3(64, 16, 5), 256, 0, stream>>>(wq, wk, wv, wp, x, wbT, xb);
    qkv_gemm_mfma<<<dim3(24, 32), 256, 0, stream>>>(xb, wbT, cosb, sinb, qb, kb, vb);
    gate_vt<<<dim3(T_SEQ/64, HD/64, NH), 256, 0, stream>>>(x, ve, wg, vb, vt);
    attn_flash<<<dim3(NH, T_SEQ/64), 256, 0, stream>>>((bf16*)qb, (bf16*)kb, (bf16*)vt, (bf16*)yb, wsz);
    proj_gemm_mfma<<<dim3(8, 32), 256, 0, stream>>>(yb, wbT + (size_t)3*EMB*EMB, out);
}

// Round 9
// 213.145 us; speedup vs baseline: 1.2212x; 1.0422x over previous
//
#include <hip/hip_runtime.h>
#include <hip/hip_bf16.h>
#include <math.h>

#define T_SEQ 4096
#define EMB   1024
#define NH    8
#define HD    128
#define HALF  64

typedef __hip_bfloat16 bf16;
typedef __attribute__((ext_vector_type(8))) short short8;
typedef __attribute__((ext_vector_type(4))) short short4v;
typedef __attribute__((ext_vector_type(4))) float float4v;

static __device__ __forceinline__ float b2f(bf16 v) { return __bfloat162float(v); }
static __device__ __forceinline__ bf16  f2b(float v) { return __float2bfloat16(v); }
static __device__ __forceinline__ short f2bs(float v) {
    bf16 h = __float2bfloat16(v); short s; __builtin_memcpy(&s, &h, 2); return s;
}
static __device__ __forceinline__ float bs2f(short s) {
    bf16 h; __builtin_memcpy(&h, &s, 2); return __bfloat162float(h);
}
// async global->LDS, 16B per lane; lds base must be wave-uniform
static __device__ __forceinline__ void gload16(const short* g, short* l) {
    __builtin_amdgcn_global_load_lds((__attribute__((address_space(1))) void*)g,
                                     (__attribute__((address_space(3))) void*)l, 16, 0, 0);
}

// ---------------------------------------------------------------------------
// Converters: z<4 -> weight transpose W[k][n] fp32 -> wbT[z][n][k] bf16
// (16 x-blocks; rest early-exit); z==4 -> x fp32 -> bf16 (64 x-blocks).
// ---------------------------------------------------------------------------
__global__ __launch_bounds__(256) void convert_all(
    const float* __restrict__ w0, const float* __restrict__ w1,
    const float* __restrict__ w2, const float* __restrict__ w3,
    const float* __restrict__ x,
    short* __restrict__ wbT, short* __restrict__ xb)
{
    const int tid = threadIdx.x;
    if (blockIdx.z == 4) {
        const int r0 = blockIdx.x * 64;
        const int c0 = blockIdx.y * 64;
        #pragma unroll
        for (int t = 0; t < 4; ++t) {
            int id = tid + t*256;
            int r = id >> 4, c4 = id & 15;
            float4 f = *(const float4*)(x + (size_t)(r0+r)*EMB + c0 + c4*4);
            short4v s = { f2bs(f.x), f2bs(f.y), f2bs(f.z), f2bs(f.w) };
            *(short4v*)(xb + (size_t)(r0+r)*EMB + c0 + c4*4) = s;
        }
        return;
    }
    if (blockIdx.x >= 16) return;
    const float* W = (blockIdx.z==0)?w0:(blockIdx.z==1)?w1:(blockIdx.z==2)?w2:w3;
    short* dst = wbT + (size_t)blockIdx.z * EMB * EMB;
    __shared__ float tile[64][65];
    const int k0 = blockIdx.x * 64;
    const int n0 = blockIdx.y * 64;
    #pragma unroll
    for (int t = 0; t < 4; ++t) {
        int id = tid + t*256;
        int r = id >> 4, c4 = id & 15;
        float4 f = *(const float4*)(W + (size_t)(k0+r)*EMB + n0 + c4*4);
        tile[r][c4*4+0]=f.x; tile[r][c4*4+1]=f.y; tile[r][c4*4+2]=f.z; tile[r][c4*4+3]=f.w;
    }
    __syncthreads();
    #pragma unroll
    for (int t = 0; t < 4; ++t) {
        int id = tid + t*256;
        int n = id >> 4, k4 = id & 15;
        short4v s;
        #pragma unroll
        for (int j = 0; j < 4; ++j) s[j] = f2bs(tile[k4*4+j][n]);
        *(short4v*)(dst + (size_t)(n0+n)*EMB + k0 + k4*4) = s;
    }
}

// ---------------------------------------------------------------------------
// MFMA GEMM, BK=64, XOR-swizzled LDS (16B unit phys = logical ^ (row&7);
// inverse permutation applied on the global source so global_load_lds's
// fixed lane->slot mapping lands data in swizzled position).
// Wave wv owns rows wv*32..+31 x all 128 cols (2x8 MFMA grid).
// Epilogues: z<2 -> register RoPE+RMS (q/k); z==2 -> +gate*ve, store
// directly transposed into vt[h][d][t].
// ---------------------------------------------------------------------------
__global__ __launch_bounds__(256) void qkv_gemm_mfma(
    const short* __restrict__ xb, const short* __restrict__ wbT,
    const float* __restrict__ cosb, const float* __restrict__ sinb,
    const float* __restrict__ x, const float* __restrict__ ve,
    const float* __restrict__ wg,
    short* __restrict__ qb, short* __restrict__ kb, short* __restrict__ vt)
{
    __shared__ short As[128*64];    // 16 KB
    __shared__ short Bs[128*64];    // 16 KB
    __shared__ float gbuf[128];
    const int n0g = blockIdx.x * 128;
    const int m0  = blockIdx.y * 128;
    const int z   = n0g >> 10;
    const int ncol0 = n0g & 1023;
    const int h = ncol0 >> 7;
    const int tid = threadIdx.x;
    const int wv = tid >> 6, lane = tid & 63;
    const int cl = lane & 15, q = lane >> 4;
    // staging decode: wave-gload = 8 rows x 128B; lane i -> row i>>3,
    // phys unit i&7, global unit (i&7)^(i>>3 & 7)
    const int lrow8 = lane >> 3;
    const int lunit = (lane & 7) ^ (lrow8 & 7);

    if (z == 2 && tid < 128) {      // per-row gate for the v epilogue
        float s = 0.f;
        #pragma unroll
        for (int c = 0; c < 32; ++c)
            s += x[(size_t)(m0 + tid)*EMB + c] * wg[c*NH + h];
        gbuf[tid] = 2.f / (1.f + __expf(-s));
    }

    float4v acc[2][8];
    #pragma unroll
    for (int mi=0;mi<2;++mi)
        #pragma unroll
        for (int ni=0;ni<8;++ni) acc[mi][ni]=(float4v){0.f,0.f,0.f,0.f};

    for (int k0 = 0; k0 < EMB; k0 += 64) {
        __syncthreads();
        #pragma unroll
        for (int t = 0; t < 4; ++t) {
            int chunk = wv*4 + t;                 // 16 chunks x 8 rows
            int row = chunk*8 + lrow8;
            gload16(xb  + (size_t)(m0  + row)*EMB + k0 + lunit*8, &As[chunk*512]);
            gload16(wbT + (size_t)(n0g + row)*EMB + k0 + lunit*8, &Bs[chunk*512]);
        }
        __syncthreads();
        #pragma unroll
        for (int ks = 0; ks < 2; ++ks) {
            const int pu = ((ks*4 + q) ^ (cl & 7)) * 8;    // swizzled unit offset
            short8 af[2], bfr[8];
            #pragma unroll
            for (int mi=0;mi<2;++mi)
                af[mi]  = *(const short8*)&As[(wv*32+mi*16+cl)*64 + pu];
            #pragma unroll
            for (int ni=0;ni<8;++ni)
                bfr[ni] = *(const short8*)&Bs[(ni*16+cl)*64 + pu];
            #pragma unroll
            for (int mi=0;mi<2;++mi)
                #pragma unroll
                for (int ni=0;ni<8;++ni)
                    acc[mi][ni] = __builtin_amdgcn_mfma_f32_16x16x32_bf16(af[mi], bfr[ni], acc[mi][ni], 0, 0, 0);
        }
    }

    if (z == 2) {   // v: add gate*ve, store transposed vt[h][d][t]
        #pragma unroll
        for (int mi=0;mi<2;++mi) {
            const int t0r = m0 + wv*32 + mi*16 + q*4;
            #pragma unroll
            for (int ni=0;ni<8;++ni) {
                const int d = ni*16 + cl;
                short4v ov;
                #pragma unroll
                for (int r=0;r<4;++r) {
                    const int t = t0r + r;
                    float v = acc[mi][ni][r]
                            + gbuf[t - m0] * ve[(size_t)t*EMB + h*HD + d];
                    ov[r] = f2bs(v);
                }
                *(short4v*)(vt + (size_t)(h*HD + d)*T_SEQ + t0r) = ov;
            }
        }
        return;
    }
    // q/k: rope + rms in registers (pair (d,d+64) = (ni, ni+4))
    short* dstb = (z == 0) ? qb : kb;
    #pragma unroll
    for (int mi=0;mi<2;++mi) {
        #pragma unroll
        for (int r=0;r<4;++r) {
            const int t = m0 + wv*32 + mi*16 + q*4 + r;
            float y1[4], y2[4];
            float ss = 0.f;
            #pragma unroll
            for (int ni=0;ni<4;++ni) {
                const int d = ni*16 + cl;
                float c = cosb[(size_t)t*HALF + d];
                float s = sinb[(size_t)t*HALF + d];
                float x1 = acc[mi][ni][r];
                float x2 = acc[mi][ni+4][r];
                y1[ni] = x1*c + x2*s;
                y2[ni] = x2*c - x1*s;
                ss += y1[ni]*y1[ni] + y2[ni]*y2[ni];
            }
            ss += __shfl_xor(ss, 1);
            ss += __shfl_xor(ss, 2);
            ss += __shfl_xor(ss, 4);
            ss += __shfl_xor(ss, 8);
            const float rr = rsqrtf(ss * (1.0f/HD) + 1e-6f);
            short* dst = dstb + (size_t)t*EMB + h*HD;
            #pragma unroll
            for (int ni=0;ni<4;++ni) {
                dst[ni*16 + cl]        = f2bs(y1[ni]*rr);
                dst[ni*16 + cl + HALF] = f2bs(y2[ni]*rr);
            }
        }
    }
}

// ---------------------------------------------------------------------------
// MFMA GEMM: out[4096,1024] fp32 = yb(bf16) @ wpT^T. 128x64 tile -> 512
// blocks = 2/CU. Wave owns 32 rows x 64 cols (2x4 MFMA grid).
// ---------------------------------------------------------------------------
__global__ __launch_bounds__(256) void proj_gemm_mfma(
    const short* __restrict__ yb, const short* __restrict__ wpT,
    float* __restrict__ out)
{
    __shared__ short As[128*32];    // 8 KB
    __shared__ short Bs[64*32];     // 4 KB
    const int n0 = blockIdx.x * 64;
    const int m0 = blockIdx.y * 128;
    const int tid = threadIdx.x;
    const int wv = tid >> 6, lane = tid & 63;
    const int cl = lane & 15, q = lane >> 4;
    const int lrow = lane >> 2;
    const int lcol = (lane & 3) * 8;
    float4v acc[2][4];
    #pragma unroll
    for (int mi=0;mi<2;++mi)
        #pragma unroll
        for (int ni=0;ni<4;++ni) acc[mi][ni]=(float4v){0.f,0.f,0.f,0.f};

    for (int k0 = 0; k0 < EMB; k0 += 32) {
        __syncthreads();
        #pragma unroll
        for (int t = 0; t < 2; ++t) {
            int chunk = wv*2 + t;
            gload16(yb + (size_t)(m0 + chunk*16 + lrow)*EMB + k0 + lcol, &As[chunk*512]);
        }
        gload16(wpT + (size_t)(n0 + wv*16 + lrow)*EMB + k0 + lcol, &Bs[wv*512]);
        __syncthreads();
        short8 af[2], bfr[4];
        #pragma unroll
        for (int mi=0;mi<2;++mi) af[mi]  = *(const short8*)&As[(wv*32+mi*16+cl)*32 + q*8];
        #pragma unroll
        for (int ni=0;ni<4;++ni) bfr[ni] = *(const short8*)&Bs[(ni*16+cl)*32 + q*8];
        #pragma unroll
        for (int mi=0;mi<2;++mi)
            #pragma unroll
            for (int ni=0;ni<4;++ni)
                acc[mi][ni] = __builtin_amdgcn_mfma_f32_16x16x32_bf16(af[mi], bfr[ni], acc[mi][ni], 0, 0, 0);
    }
    #pragma unroll
    for (int mi=0;mi<2;++mi)
        #pragma unroll
        for (int ni=0;ni<4;++ni)
            #pragma unroll
            for (int r=0;r<4;++r)
                out[(size_t)(m0+wv*32+mi*16+q*4+r)*EMB + n0 + ni*16+cl] = acc[mi][ni][r];
}

// ---------------------------------------------------------------------------
// Flash attention, MFMA 16x16x32 bf16. One block = 64 queries x 1 head.
// grid = (head, qtile) so linear%8 = head -> one head's K/V per XCD L2.
// ---------------------------------------------------------------------------
__global__ __launch_bounds__(256) void attn_flash(
    const bf16* __restrict__ qbh, const bf16* __restrict__ kbh,
    const bf16* __restrict__ vth, bf16* __restrict__ ybh,
    const int* __restrict__ wptr)
{
    const short* qb = (const short*)qbh;
    const short* kb = (const short*)kbh;
    const short* vt = (const short*)vth;
    short* yb = (short*)ybh;

    __shared__ short Ks[64*136];
    __shared__ short Vs[128*72];
    __shared__ short Ps[4*16*72];

    int W = *wptr; W = min(max(W, 1), 1024);
    const int h  = blockIdx.x;
    const int i0 = blockIdx.y * 64;
    const int tid  = threadIdx.x;
    const int wv   = tid >> 6;
    const int lane = tid & 63;
    const int cl   = lane & 15;
    const int q    = lane >> 4;
    const int m0   = wv * 16;
    const float scale = 0.08838834764831845f;

    short8 qa[4];
    {
        const short* qbase = qb + (size_t)(i0 + m0 + cl) * EMB + h*HD + q*8;
        #pragma unroll
        for (int ks = 0; ks < 4; ++ks)
            qa[ks] = *(const short8*)(qbase + ks*32);
    }

    float4v o[8];
    #pragma unroll
    for (int n = 0; n < 8; ++n) o[n] = (float4v){0.f,0.f,0.f,0.f};
    float lrow[4] = {0.f,0.f,0.f,0.f};

    const int lo_key  = i0 - W + 1;
    const int jt_start = lo_key > 0 ? (lo_key >> 6) : 0;
    const int jt_end   = i0 >> 6;

    const int kkey[4] = { (tid+0)>>4, (tid+256)>>4, (tid+512)>>4, (tid+768)>>4 };
    const int kc16 = tid & 15;
    const int vd[4] = { (tid+0)>>3, (tid+256)>>3, (tid+512)>>3, (tid+768)>>3 };
    const int vc8 = tid & 7;

    short8 kreg[4], vreg[4];
    {
        const int j0 = jt_start << 6;
        #pragma unroll
        for (int kk = 0; kk < 4; ++kk) {
            kreg[kk] = *(const short8*)(kb + (size_t)(j0+kkey[kk])*EMB + h*HD + kc16*8);
            vreg[kk] = *(const short8*)(vt + (size_t)(h*HD + vd[kk])*T_SEQ + j0 + vc8*8);
        }
    }

    for (int jt = jt_start; jt <= jt_end; ++jt) {
        const int j0 = jt << 6;
        __syncthreads();
        #pragma unroll
        for (int kk = 0; kk < 4; ++kk) {
            *(short8*)&Ks[kkey[kk]*136 + kc16*8] = kreg[kk];
            *(short8*)&Vs[vd[kk]*72 + vc8*8]     = vreg[kk];
        }
        __syncthreads();
        if (jt < jt_end) {
            const int j0n = j0 + 64;
            #pragma unroll
            for (int kk = 0; kk < 4; ++kk) {
                kreg[kk] = *(const short8*)(kb + (size_t)(j0n+kkey[kk])*EMB + h*HD + kc16*8);
                vreg[kk] = *(const short8*)(vt + (size_t)(h*HD + vd[kk])*T_SEQ + j0n + vc8*8);
            }
        }

        float4v s[4];
        #pragma unroll
        for (int nt = 0; nt < 4; ++nt) {
            s[nt] = (float4v){0.f,0.f,0.f,0.f};
            #pragma unroll
            for (int ks = 0; ks < 4; ++ks) {
                short8 kf = *(const short8*)&Ks[(nt*16 + cl)*136 + ks*32 + q*8];
                s[nt] = __builtin_amdgcn_mfma_f32_16x16x32_bf16(qa[ks], kf, s[nt], 0, 0, 0);
            }
        }
        const bool needmask = (j0 + 63 > i0) || (j0 < i0 + 64 - W);
        #pragma unroll
        for (int nt = 0; nt < 4; ++nt) {
            #pragma unroll
            for (int r = 0; r < 4; ++r) {
                float sv = s[nt][r] * scale;
                if (needmask) {
                    int j    = j0 + nt*16 + cl;
                    int irow = i0 + m0 + q*4 + r;
                    if (j > irow || j <= irow - W) sv = -1e30f;
                }
                s[nt][r] = __expf(sv);
            }
        }
        #pragma unroll
        for (int r = 0; r < 4; ++r)
            lrow[r] += s[0][r] + s[1][r] + s[2][r] + s[3][r];
        #pragma unroll
        for (int nt = 0; nt < 4; ++nt)
            #pragma unroll
            for (int r = 0; r < 4; ++r)
                Ps[wv*1152 + (q*4+r)*72 + nt*16 + cl] = f2bs(s[nt][r]);
        short8 pa[2];
        #pragma unroll
        for (int k2 = 0; k2 < 2; ++k2)
            pa[k2] = *(const short8*)&Ps[wv*1152 + cl*72 + k2*32 + q*8];
        #pragma unroll
        for (int n = 0; n < 8; ++n) {
            #pragma unroll
            for (int k2 = 0; k2 < 2; ++k2) {
                short8 vf = *(const short8*)&Vs[(n*16 + cl)*72 + k2*32 + q*8];
                o[n] = __builtin_amdgcn_mfma_f32_16x16x32_bf16(pa[k2], vf, o[n], 0, 0, 0);
            }
        }
    }
    #pragma unroll
    for (int r = 0; r < 4; ++r) {
        float t = lrow[r];
        t += __shfl_xor(t, 1);
        t += __shfl_xor(t, 2);
        t += __shfl_xor(t, 4);
        t += __shfl_xor(t, 8);
        float inv = 1.f / t;
        int row = i0 + m0 + q*4 + r;
        #pragma unroll
        for (int n = 0; n < 8; ++n)
            yb[(size_t)row*EMB + h*HD + n*16 + cl] = f2bs(o[n][r] * inv);
    }
}

// ---------------------------------------------------------------------------
extern "C" void kernel_launch(void* const* d_in, const int* in_sizes, int n_in,
                              void* d_out, int out_size, void* d_ws, size_t ws_size,
                              hipStream_t stream)
{
    const float* x    = (const float*)d_in[0];
    const float* ve   = (const float*)d_in[1];
    const float* cosb = (const float*)d_in[2];
    const float* sinb = (const float*)d_in[3];
    const float* wq   = (const float*)d_in[4];
    const float* wk   = (const float*)d_in[5];
    const float* wv   = (const float*)d_in[6];
    const float* wg   = (const float*)d_in[7];
    const float* wp   = (const float*)d_in[8];
    const int*   wsz  = (const int*)d_in[9];
    float* out = (float*)d_out;

    const size_t SEG = (size_t)T_SEQ * EMB;        // 4M elements = 8 MB bf16
    short* xb  = (short*)d_ws;                     // read only by qkv
    short* wbT = xb + SEG;                         // wq|wk|wv|wp transposed
    short* qb  = wbT + SEG;
    short* kb  = qb + SEG;
    short* vt  = kb + SEG;                         // 40 MB total
    short* yb  = xb;                               // alias: xb dead after qkv

    convert_all<<<dim3(64, 16, 5), 256, 0, stream>>>(wq, wk, wv, wp, x, wbT, xb);
    qkv_gemm_mfma<<<dim3(24, 32), 256, 0, stream>>>(xb, wbT, cosb, sinb,
                                                    x, ve, wg, qb, kb, vt);
    attn_flash<<<dim3(NH, T_SEQ/64), 256, 0, stream>>>((bf16*)qb, (bf16*)kb, (bf16*)vt, (bf16*)yb, wsz);
    proj_gemm_mfma<<<dim3(16, 32), 256, 0, stream>>>(yb, wbT + (size_t)3*EMB*EMB, out);
}